// Round 13
// baseline (389.581 us; speedup 1.0000x reference)
//
#include <hip/hip_runtime.h>
#include <hip/hip_bf16.h>
#include <hip/hip_fp16.h>
#include <math.h>

// Problem constants (match reference)
#define NN 100000
#define EE 1600000
#define HH 128
#define GG 2000
#define SS 200
#define CC 10
#define NPG 50   // nodes per graph
#define PGS 10   // graphs per set
#define NCLS 128           // dst classes (one persistent block per class in count/fill)
#define CLSW 782           // ceil(NN/NCLS); 128*782 = 100096 >= NN
#define EPB 4096           // edges per histogram/scatter block
#define NBLKH 391          // ceil(EE/EPB)
#define SCAN_N (NCLS * NBLKH)   // 50048

typedef _Float16 f16x8 __attribute__((ext_vector_type(8)));
typedef float    f32x4 __attribute__((ext_vector_type(4)));

// packed edge-in-bin: bits [16:0] = src (<131072), bits [26:17] = d - class_base (<1024)

// ---------------- CSR build (deterministic binned, class-owned fill) ----------------

__global__ __launch_bounds__(256) void histo_kernel(const int* __restrict__ ei_dst,
                                                    int* __restrict__ blkcnt) {
    __shared__ int h[4][NCLS];
    for (int i = threadIdx.x; i < 4 * NCLS; i += 256) ((int*)h)[i] = 0;
    __syncthreads();
    int w = threadIdx.x >> 6;
    int base = blockIdx.x * EPB;
#pragma unroll
    for (int i = 0; i < 16; ++i) {
        int idx = base + i * 256 + threadIdx.x;
        if (idx < EE) {
            int d = __builtin_nontemporal_load(ei_dst + idx);
            atomicAdd(&h[w][(unsigned)d / CLSW], 1);
        }
    }
    __syncthreads();
    for (int c = threadIdx.x; c < NCLS; c += 256)
        blkcnt[c * NBLKH + blockIdx.x] = h[0][c] + h[1][c] + h[2][c] + h[3][c];
}

// generic 3-phase scan: out[i+1] = inclusive_scan(v)[i], out[0] = 0  (=> out = exclusive scan)
__global__ void scan_chunk_kernel(const int* __restrict__ v, int* __restrict__ outp,
                                  int* __restrict__ bsum, int n) {
    __shared__ int s[256];
    int tid = threadIdx.x;
    int i = blockIdx.x * 256 + tid;
    int x = (i < n) ? v[i] : 0;
    s[tid] = x;
    __syncthreads();
    for (int off = 1; off < 256; off <<= 1) {
        int y = (tid >= off) ? s[tid - off] : 0;
        __syncthreads();
        s[tid] += y;
        __syncthreads();
    }
    if (i < n) outp[i + 1] = s[tid];
    if (tid == 255) bsum[blockIdx.x] = s[255];
}

__global__ void scan_bsums_kernel(int* bsum, int nb) {
    __shared__ int s[512];
    int tid = threadIdx.x;
    int x = (tid < nb) ? bsum[tid] : 0;
    s[tid] = x;
    __syncthreads();
    for (int off = 1; off < 512; off <<= 1) {
        int y = (tid >= off) ? s[tid - off] : 0;
        __syncthreads();
        s[tid] += y;
        __syncthreads();
    }
    if (tid < nb) bsum[tid] = s[tid];
}

__global__ void scan_finish_kernel(int* __restrict__ outp, const int* __restrict__ bsum, int n) {
    int i = blockIdx.x * 256 + threadIdx.x;
    if (i < n) {
        if (blockIdx.x > 0) outp[i + 1] += bsum[blockIdx.x - 1];
    }
    if (i == 0) outp[0] = 0;
}

// scatter edges into packed class buckets (LDS cursors only, 4B payload)
__global__ __launch_bounds__(256) void scatter_bin_kernel(const int* __restrict__ ei,
                                                          const int* __restrict__ blkoff,
                                                          unsigned int* __restrict__ ebin) {
    __shared__ int cur[NCLS];
    for (int c = threadIdx.x; c < NCLS; c += 256) cur[c] = blkoff[c * NBLKH + blockIdx.x];
    __syncthreads();
    int base = blockIdx.x * EPB;
#pragma unroll
    for (int i = 0; i < 16; ++i) {
        int idx = base + i * 256 + threadIdx.x;
        if (idx < EE) {
            int s = __builtin_nontemporal_load(ei + idx);
            int d = __builtin_nontemporal_load(ei + EE + idx);
            int c = (unsigned)d / CLSW;
            int pos = atomicAdd(&cur[c], 1);
            ebin[pos] = ((unsigned)(d - c * CLSW) << 17) | (unsigned)s;
        }
    }
}

// one block per class: LDS degree count -> row_ptr (class-local prefix scan) + dinv.
__global__ __launch_bounds__(256) void count_dinv_kernel(const unsigned int* __restrict__ ebin,
                                                         const int* __restrict__ blkoff,
                                                         int* __restrict__ row_ptr,
                                                         float* __restrict__ dinv) {
    __shared__ int cnt[CLSW];
    __shared__ int part[256];
    int c = blockIdx.x;
    for (int i = threadIdx.x; i < CLSW; i += 256) cnt[i] = 0;
    __syncthreads();
    int beg = blkoff[c * NBLKH];
    int end = blkoff[(c + 1) * NBLKH];   // blkoff[SCAN_N] == EE
    int n0 = c * CLSW;
    for (int k = beg + threadIdx.x; k < end; k += 256) {
        unsigned int e = __builtin_nontemporal_load(ebin + k);
        atomicAdd(&cnt[e >> 17], 1);
    }
    __syncthreads();
    int nn = min(n0 + CLSW, NN) - n0;
    int t = threadIdx.x;
    int base = t * 4;
    int lpre[4];
    int lsum = 0;
#pragma unroll
    for (int i = 0; i < 4; ++i) {
        int idx = base + i;
        int v = (idx < nn) ? cnt[idx] : 0;
        lpre[i] = lsum;
        lsum += v;
    }
    part[t] = lsum;
    __syncthreads();
    for (int off = 1; off < 256; off <<= 1) {
        int y = (t >= off) ? part[t - off] : 0;
        __syncthreads();
        part[t] += y;
        __syncthreads();
    }
    int add = beg + ((t > 0) ? part[t - 1] : 0);
#pragma unroll
    for (int i = 0; i < 4; ++i) {
        int idx = base + i;
        if (idx < nn) {
            row_ptr[n0 + idx] = add + lpre[i];
            dinv[n0 + idx] = 1.0f / sqrtf((float)(cnt[idx] + 1));  // +1 self loop
        }
    }
    if (t == 0) row_ptr[n0 + nn] = end;   // class boundary (last class writes row_ptr[NN]=EE)
}

// one block per class: LDS cursors from row_ptr, fill col (class-owned col range).
__global__ __launch_bounds__(256) void fill_class_kernel(const unsigned int* __restrict__ ebin,
                                                         const int* __restrict__ blkoff,
                                                         const int* __restrict__ row_ptr,
                                                         int* __restrict__ col) {
    __shared__ int cur[CLSW];
    int c = blockIdx.x;
    int n0 = c * CLSW;
    int nn = min(n0 + CLSW, NN) - n0;
    for (int i = threadIdx.x; i < nn; i += 256) cur[i] = row_ptr[n0 + i];
    __syncthreads();
    int beg = blkoff[c * NBLKH];
    int end = blkoff[(c + 1) * NBLKH];
    for (int k = beg + threadIdx.x; k < end; k += 256) {
        unsigned int e = __builtin_nontemporal_load(ebin + k);
        int o = atomicAdd(&cur[e >> 17], 1);
        col[o] = (int)(e & 0x1FFFFu);
    }
}

// ---------------- W transpose precompute: Wt[c][k] = (fp16) W[k][c], 3 matrices -------------

__global__ __launch_bounds__(256) void wt_kernel(const float* __restrict__ W1,
                                                 const float* __restrict__ W2,
                                                 const float* __restrict__ W3,
                                                 _Float16* __restrict__ wt) {
    int m = blockIdx.y;
    const float* W = (m == 0) ? W1 : ((m == 1) ? W2 : W3);
    _Float16* o = wt + (size_t)m * 16384;
    int f = blockIdx.x * 256 + threadIdx.x;   // float4 id in [0,4096)
    float4 v = ((const float4*)W)[f];
    int k = f >> 5;
    int c = (f & 31) << 2;
    o[(c + 0) * 128 + k] = (_Float16)v.x;
    o[(c + 1) * 128 + k] = (_Float16)v.y;
    o[(c + 2) * 128 + k] = (_Float16)v.z;
    o[(c + 3) * 128 + k] = (_Float16)v.w;
}

// ---------------- MFMA GEMM: Y[n][128](fp16, x dinv[row]) = X[n][128] @ W ----------
// B-fragments read directly from precomputed global Wt (32KB, L2-resident) — no W LDS
// staging, LDS = output buffer only (34.8KB) -> 4 blocks/CU.

#define WTP 136

template <bool IN32>
__global__ __launch_bounds__(256) void gemm_mfma_kernel(const void* __restrict__ Xv,
                                                        const _Float16* __restrict__ Wt,
                                                        const float* __restrict__ dinv,
                                                        _Float16* __restrict__ Y, int nrows) {
    __shared__ _Float16 Ob[128][WTP];   // 34.8 KB
    int tid = threadIdx.x;
    int row0 = blockIdx.x * 128;

    int wave = tid >> 6;
    int l = tid & 63;
    int arow = l & 15;
    int kg = l >> 4;                 // k-group 0..3
    int baseRow = row0 + wave * 32;

    // A fragments: lane holds X[row][ks*32 + kg*8 .. +8]
    f16x8 afrag[2][4];
#pragma unroll
    for (int rt = 0; rt < 2; ++rt) {
        int r = baseRow + rt * 16 + arow;
        r = min(r, nrows - 1);
        if (IN32) {
            const float* xr = ((const float*)Xv) + (size_t)r * 128;
#pragma unroll
            for (int ks = 0; ks < 4; ++ks) {
                int k0 = ks * 32 + kg * 8;
                float4 a = ((const float4*)xr)[k0 >> 2];
                float4 b = ((const float4*)xr)[(k0 >> 2) + 1];
                f16x8 v;
                v[0] = (_Float16)a.x; v[1] = (_Float16)a.y;
                v[2] = (_Float16)a.z; v[3] = (_Float16)a.w;
                v[4] = (_Float16)b.x; v[5] = (_Float16)b.y;
                v[6] = (_Float16)b.z; v[7] = (_Float16)b.w;
                afrag[rt][ks] = v;
            }
        } else {
            const f16x8* xr = (const f16x8*)(((const _Float16*)Xv) + (size_t)r * 128);
#pragma unroll
            for (int ks = 0; ks < 4; ++ks) afrag[rt][ks] = xr[ks * 4 + kg];
        }
    }

    f32x4 acc[2][8];
#pragma unroll
    for (int rt = 0; rt < 2; ++rt)
#pragma unroll
        for (int ct = 0; ct < 8; ++ct) acc[rt][ct] = (f32x4){0.f, 0.f, 0.f, 0.f};

#pragma unroll
    for (int ct = 0; ct < 8; ++ct) {
#pragma unroll
        for (int ks = 0; ks < 4; ++ks) {
            f16x8 b = *(const f16x8*)(Wt + (size_t)(ct * 16 + arow) * 128 + ks * 32 + kg * 8);
            acc[0][ct] = __builtin_amdgcn_mfma_f32_16x16x32_f16(afrag[0][ks], b, acc[0][ct], 0, 0, 0);
            acc[1][ct] = __builtin_amdgcn_mfma_f32_16x16x32_f16(afrag[1][ks], b, acc[1][ct], 0, 0, 0);
        }
    }

    // dinv for the 8 rows this lane owns (D: row = rt*16 + 4*kg + j, col = arow)
    float dv[2][4];
#pragma unroll
    for (int rt = 0; rt < 2; ++rt)
#pragma unroll
        for (int j = 0; j < 4; ++j) {
            int r = baseRow + rt * 16 + 4 * kg + j;
            dv[rt][j] = dinv[min(r, nrows - 1)];
        }

    // stage to LDS (own wave's 32 rows only — no block sync needed)
#pragma unroll
    for (int rt = 0; rt < 2; ++rt)
#pragma unroll
        for (int ct = 0; ct < 8; ++ct)
#pragma unroll
            for (int j = 0; j < 4; ++j)
                Ob[wave * 32 + rt * 16 + 4 * kg + j][ct * 16 + arow] =
                    (_Float16)(acc[rt][ct][j] * dv[rt][j]);

    // coalesced write-back: 8 x 16B per lane
#pragma unroll
    for (int i = 0; i < 8; ++i) {
        int q = i * 64 + l;          // [0,512): 32 rows x 16 chunks
        int lrow = q >> 4;
        int c = q & 15;
        int r = baseRow + lrow;
        if (r < nrows) {
            f16x8 v = *(const f16x8*)&Ob[wave * 32 + lrow][c * 8];
            *(f16x8*)(Y + (size_t)r * 128 + c * 8) = v;
        }
    }
}

// ---------------- GCN aggregation (proven layout, 16-deep unroll) ----------------
// one wave per node, lane = half2 feature slot. out = relu(dinv[i]*(sum+self) + b), fp16.

__global__ __launch_bounds__(256) void aggregate_kernel(const __half* __restrict__ hw,
                                                        const int* __restrict__ rp,
                                                        const int* __restrict__ col,
                                                        const float* __restrict__ dinv,
                                                        const float* __restrict__ bias,
                                                        __half* __restrict__ outp, int n) {
    int wid = threadIdx.x >> 6;
    int lane = threadIdx.x & 63;
    int i = blockIdx.x * 4 + wid;
    if (i >= n) return;
    const __half2* hw2 = (const __half2*)hw;  // row = 64 half2 (256B)
    float2 a0, a1, a2, a3;
    {
        float2 self = __half22float2(hw2[(size_t)i * 64 + lane]);
        a0.x = self.x; a0.y = self.y;
    }
    a1 = make_float2(0.f, 0.f);
    a2 = make_float2(0.f, 0.f);
    a3 = make_float2(0.f, 0.f);
    int j0 = rp[i], j1 = rp[i + 1];
    int j = j0;
    for (; j + 16 <= j1; j += 16) {
        int s0 = col[j + 0];
        int s1 = col[j + 1];
        int s2 = col[j + 2];
        int s3 = col[j + 3];
        int s4 = col[j + 4];
        int s5 = col[j + 5];
        int s6 = col[j + 6];
        int s7 = col[j + 7];
        int s8 = col[j + 8];
        int s9 = col[j + 9];
        int s10 = col[j + 10];
        int s11 = col[j + 11];
        int s12 = col[j + 12];
        int s13 = col[j + 13];
        int s14 = col[j + 14];
        int s15 = col[j + 15];
        __half2 v0 = hw2[(size_t)s0 * 64 + lane];
        __half2 v1 = hw2[(size_t)s1 * 64 + lane];
        __half2 v2 = hw2[(size_t)s2 * 64 + lane];
        __half2 v3 = hw2[(size_t)s3 * 64 + lane];
        __half2 v4 = hw2[(size_t)s4 * 64 + lane];
        __half2 v5 = hw2[(size_t)s5 * 64 + lane];
        __half2 v6 = hw2[(size_t)s6 * 64 + lane];
        __half2 v7 = hw2[(size_t)s7 * 64 + lane];
        __half2 v8 = hw2[(size_t)s8 * 64 + lane];
        __half2 v9 = hw2[(size_t)s9 * 64 + lane];
        __half2 v10 = hw2[(size_t)s10 * 64 + lane];
        __half2 v11 = hw2[(size_t)s11 * 64 + lane];
        __half2 v12 = hw2[(size_t)s12 * 64 + lane];
        __half2 v13 = hw2[(size_t)s13 * 64 + lane];
        __half2 v14 = hw2[(size_t)s14 * 64 + lane];
        __half2 v15 = hw2[(size_t)s15 * 64 + lane];
        float2 f;
        f = __half22float2(v0);  a0.x += f.x; a0.y += f.y;
        f = __half22float2(v1);  a1.x += f.x; a1.y += f.y;
        f = __half22float2(v2);  a2.x += f.x; a2.y += f.y;
        f = __half22float2(v3);  a3.x += f.x; a3.y += f.y;
        f = __half22float2(v4);  a0.x += f.x; a0.y += f.y;
        f = __half22float2(v5);  a1.x += f.x; a1.y += f.y;
        f = __half22float2(v6);  a2.x += f.x; a2.y += f.y;
        f = __half22float2(v7);  a3.x += f.x; a3.y += f.y;
        f = __half22float2(v8);  a0.x += f.x; a0.y += f.y;
        f = __half22float2(v9);  a1.x += f.x; a1.y += f.y;
        f = __half22float2(v10); a2.x += f.x; a2.y += f.y;
        f = __half22float2(v11); a3.x += f.x; a3.y += f.y;
        f = __half22float2(v12); a0.x += f.x; a0.y += f.y;
        f = __half22float2(v13); a1.x += f.x; a1.y += f.y;
        f = __half22float2(v14); a2.x += f.x; a2.y += f.y;
        f = __half22float2(v15); a3.x += f.x; a3.y += f.y;
    }
    for (; j + 4 <= j1; j += 4) {
        int s0 = col[j + 0];
        int s1 = col[j + 1];
        int s2 = col[j + 2];
        int s3 = col[j + 3];
        __half2 v0 = hw2[(size_t)s0 * 64 + lane];
        __half2 v1 = hw2[(size_t)s1 * 64 + lane];
        __half2 v2 = hw2[(size_t)s2 * 64 + lane];
        __half2 v3 = hw2[(size_t)s3 * 64 + lane];
        float2 f;
        f = __half22float2(v0); a0.x += f.x; a0.y += f.y;
        f = __half22float2(v1); a1.x += f.x; a1.y += f.y;
        f = __half22float2(v2); a2.x += f.x; a2.y += f.y;
        f = __half22float2(v3); a3.x += f.x; a3.y += f.y;
    }
    for (; j < j1; ++j) {
        int s = col[j];
        float2 f = __half22float2(hw2[(size_t)s * 64 + lane]);
        a0.x += f.x; a0.y += f.y;
    }
    float di = dinv[i];
    float2 acc;
    acc.x = ((a0.x + a1.x) + (a2.x + a3.x)) * di;
    acc.y = ((a0.y + a1.y) + (a2.y + a3.y)) * di;
    float2 bv = ((const float2*)bias)[lane];
    float rx = fmaxf(acc.x + bv.x, 0.f);
    float ry = fmaxf(acc.y + bv.y, 0.f);
    ((__half2*)outp)[(size_t)i * 64 + lane] = __floats2half2_rn(rx, ry);
}

// ---------------- fused mean-pool + DeepSets psi (one block per graph) ----------------

__global__ __launch_bounds__(256) void poolpsi_kernel(const __half* __restrict__ h,
                                                      const float* __restrict__ W1,
                                                      const float* __restrict__ b1,
                                                      const float* __restrict__ W2,
                                                      const float* __restrict__ b2,
                                                      float* __restrict__ pbuf) {
    __shared__ float2 part[4][64];
    __shared__ float e[128];
    __shared__ float t[128];
    int g = blockIdx.x;
    int q = threadIdx.x & 63;
    int rg = threadIdx.x >> 6;
    const __half2* h2 = (const __half2*)h;
    size_t base = (size_t)g * NPG * 64;
    float2 acc = {0.f, 0.f};
    for (int r = rg; r < NPG; r += 4) {
        float2 v = __half22float2(h2[base + (size_t)r * 64 + q]);
        acc.x += v.x;
        acc.y += v.y;
    }
    part[rg][q] = acc;
    __syncthreads();
    if (threadIdx.x < 64) {
        float2 s0 = part[0][threadIdx.x];
        float2 s1 = part[1][threadIdx.x];
        float2 s2 = part[2][threadIdx.x];
        float2 s3 = part[3][threadIdx.x];
        e[2 * threadIdx.x]     = ((s0.x + s1.x) + (s2.x + s3.x)) * (1.0f / NPG);
        e[2 * threadIdx.x + 1] = ((s0.y + s1.y) + (s2.y + s3.y)) * (1.0f / NPG);
    }
    __syncthreads();
    int c = threadIdx.x;
    float acc1 = 0.f, acc2 = 0.f;
    if (c < 128) {
        acc1 = b1[c];
#pragma unroll 8
        for (int k = 0; k < 128; ++k) acc1 += e[k] * W1[k * 128 + c];
        t[c] = fmaxf(acc1, 0.f);
    }
    __syncthreads();
    if (c < 128) {
        acc2 = b2[c];
#pragma unroll 8
        for (int k = 0; k < 128; ++k) acc2 += t[k] * W2[k * 128 + c];
        pbuf[(size_t)g * 128 + c] = tanhf(acc2);
    }
}

// ---------------- set-sum + phi head ----------------

__global__ __launch_bounds__(128) void phi_kernel(const float* __restrict__ pbuf,
                                                  const float* __restrict__ W1,
                                                  const float* __restrict__ b1,
                                                  const float* __restrict__ W2,
                                                  const float* __restrict__ b2,
                                                  float* __restrict__ out) {
    __shared__ float a[128];
    __shared__ float u[128];
    int s = blockIdx.x;
    int c = threadIdx.x;
    float acc = 0.f;
#pragma unroll
    for (int p = 0; p < PGS; ++p) acc += pbuf[(size_t)(s + p * SS) * 128 + c];
    a[c] = acc;
    __syncthreads();
    float acc1 = b1[c];
#pragma unroll 8
    for (int k = 0; k < 128; ++k) acc1 += a[k] * W1[k * 128 + c];
    u[c] = fmaxf(acc1, 0.f);
    __syncthreads();
    if (c < CC) {
        float acc2 = b2[c];
#pragma unroll 8
        for (int k = 0; k < 128; ++k) acc2 += u[k] * W2[k * CC + c];
        out[(size_t)s * CC + c] = acc2;
    }
}

// ---------------- launch ----------------

extern "C" void kernel_launch(void* const* d_in, const int* in_sizes, int n_in,
                              void* d_out, int out_size, void* d_ws, size_t ws_size,
                              hipStream_t stream) {
    const float* x   = (const float*)d_in[0];
    const int* ei    = (const int*)d_in[1];
    const float* W1  = (const float*)d_in[4];
    const float* b1  = (const float*)d_in[5];
    const float* W2  = (const float*)d_in[6];
    const float* b2  = (const float*)d_in[7];
    const float* W3  = (const float*)d_in[8];
    const float* b3  = (const float*)d_in[9];
    const float* pW1 = (const float*)d_in[10];
    const float* pb1 = (const float*)d_in[11];
    const float* pW2 = (const float*)d_in[12];
    const float* pb2 = (const float*)d_in[13];
    const float* fW1 = (const float*)d_in[14];
    const float* fb1 = (const float*)d_in[15];
    const float* fW2 = (const float*)d_in[16];
    const float* fb2 = (const float*)d_in[17];
    float* out = (float*)d_out;

    // workspace carve-up (256B aligned)
    char* p = (char*)d_ws;
    auto alloc = [&](size_t bytes) {
        char* r = p;
        p += (bytes + 255) & ~(size_t)255;
        return r;
    };
    float*        dinv    = (float*)alloc((size_t)NN * 4);
    int*          row_ptr = (int*)alloc((size_t)(NN + 1) * 4);
    int*          bsum2   = (int*)alloc(512 * 4);
    int*          blkcnt  = (int*)alloc((size_t)SCAN_N * 4);
    int*          blkoff  = (int*)alloc((size_t)(SCAN_N + 1) * 4);
    int*          col     = (int*)alloc((size_t)EE * 4);
    unsigned int* ebin    = (unsigned int*)alloc((size_t)EE * 4);   // 6.4 MB packed buckets
    _Float16*     wtbuf   = (_Float16*)alloc((size_t)3 * 16384 * 2); // 3 transposed fp16 weights
    _Float16*     bufA    = (_Float16*)alloc((size_t)NN * HH * 2);  // dinv-scaled XW (gather operand)
    __half*       bufB    = (__half*)alloc((size_t)NN * HH * 2);    // relu'd layer output
    float*        pbuf    = (float*)alloc((size_t)GG * HH * 4);

    const int nblkS = (SCAN_N + 255) / 256;    // 196

    // weight transposes (independent of CSR chain)
    wt_kernel<<<dim3(16, 3), 256, 0, stream>>>(W1, W2, W3, wtbuf);

    // CSR build (deterministic binned, class-owned)
    histo_kernel<<<NBLKH, 256, 0, stream>>>(ei + EE, blkcnt);
    scan_chunk_kernel<<<nblkS, 256, 0, stream>>>(blkcnt, blkoff, bsum2, SCAN_N);
    scan_bsums_kernel<<<1, 512, 0, stream>>>(bsum2, nblkS);
    scan_finish_kernel<<<nblkS, 256, 0, stream>>>(blkoff, bsum2, SCAN_N);
    scatter_bin_kernel<<<NBLKH, 256, 0, stream>>>(ei, blkoff, ebin);
    count_dinv_kernel<<<NCLS, 256, 0, stream>>>(ebin, blkoff, row_ptr, dinv);
    fill_class_kernel<<<NCLS, 256, 0, stream>>>(ebin, blkoff, row_ptr, col);

    const int gemmBlocks = (NN + 127) / 128;   // 782
    const int aggBlocks  = (NN + 3) / 4;       // 25000

    // layer 1
    gemm_mfma_kernel<true><<<gemmBlocks, 256, 0, stream>>>(x, wtbuf, dinv, bufA, NN);
    aggregate_kernel<<<aggBlocks, 256, 0, stream>>>((const __half*)bufA, row_ptr, col, dinv, b1, bufB, NN);
    // layer 2
    gemm_mfma_kernel<false><<<gemmBlocks, 256, 0, stream>>>(bufB, wtbuf + 16384, dinv, bufA, NN);
    aggregate_kernel<<<aggBlocks, 256, 0, stream>>>((const __half*)bufA, row_ptr, col, dinv, b2, bufB, NN);
    // layer 3
    gemm_mfma_kernel<false><<<gemmBlocks, 256, 0, stream>>>(bufB, wtbuf + 32768, dinv, bufA, NN);
    aggregate_kernel<<<aggBlocks, 256, 0, stream>>>((const __half*)bufA, row_ptr, col, dinv, b3, bufB, NN);

    // fused pool+psi -> pbuf
    poolpsi_kernel<<<GG, 256, 0, stream>>>(bufB, pW1, pb1, pW2, pb2, pbuf);
    // phi head
    phi_kernel<<<SS, 128, 0, stream>>>(pbuf, fW1, fb1, fW2, fb2, out);
}

// Round 14
// 374.613 us; speedup vs baseline: 1.0400x; 1.0400x over previous
//
#include <hip/hip_runtime.h>
#include <hip/hip_bf16.h>
#include <hip/hip_fp16.h>
#include <math.h>

// Problem constants (match reference)
#define NN 100000
#define EE 1600000
#define HH 128
#define GG 2000
#define SS 200
#define CC 10
#define NPG 50   // nodes per graph
#define PGS 10   // graphs per set
#define NCLS 128           // dst classes (one persistent block per class in count/fill)
#define CLSW 782           // ceil(NN/NCLS); 128*782 = 100096 >= NN
#define EPB 4096           // edges per histogram/scatter block
#define NBLKH 391          // ceil(EE/EPB)
#define SCAN_N (NCLS * NBLKH)   // 50048

typedef _Float16 f16x8 __attribute__((ext_vector_type(8)));
typedef float    f32x4 __attribute__((ext_vector_type(4)));

// packed edge-in-bin: bits [16:0] = src (<131072), bits [26:17] = d - class_base (<1024)

// ---------------- CSR build (deterministic binned, class-owned fill) ----------------

__global__ __launch_bounds__(256) void histo_kernel(const int* __restrict__ ei_dst,
                                                    int* __restrict__ blkcnt) {
    __shared__ int h[4][NCLS];
    for (int i = threadIdx.x; i < 4 * NCLS; i += 256) ((int*)h)[i] = 0;
    __syncthreads();
    int w = threadIdx.x >> 6;
    int base = blockIdx.x * EPB;
#pragma unroll
    for (int i = 0; i < 16; ++i) {
        int idx = base + i * 256 + threadIdx.x;
        if (idx < EE) {
            int d = __builtin_nontemporal_load(ei_dst + idx);
            atomicAdd(&h[w][(unsigned)d / CLSW], 1);
        }
    }
    __syncthreads();
    for (int c = threadIdx.x; c < NCLS; c += 256)
        blkcnt[c * NBLKH + blockIdx.x] = h[0][c] + h[1][c] + h[2][c] + h[3][c];
}

// generic 3-phase scan: out[i+1] = inclusive_scan(v)[i], out[0] = 0  (=> out = exclusive scan)
__global__ void scan_chunk_kernel(const int* __restrict__ v, int* __restrict__ outp,
                                  int* __restrict__ bsum, int n) {
    __shared__ int s[256];
    int tid = threadIdx.x;
    int i = blockIdx.x * 256 + tid;
    int x = (i < n) ? v[i] : 0;
    s[tid] = x;
    __syncthreads();
    for (int off = 1; off < 256; off <<= 1) {
        int y = (tid >= off) ? s[tid - off] : 0;
        __syncthreads();
        s[tid] += y;
        __syncthreads();
    }
    if (i < n) outp[i + 1] = s[tid];
    if (tid == 255) bsum[blockIdx.x] = s[255];
}

__global__ void scan_bsums_kernel(int* bsum, int nb) {
    __shared__ int s[512];
    int tid = threadIdx.x;
    int x = (tid < nb) ? bsum[tid] : 0;
    s[tid] = x;
    __syncthreads();
    for (int off = 1; off < 512; off <<= 1) {
        int y = (tid >= off) ? s[tid - off] : 0;
        __syncthreads();
        s[tid] += y;
        __syncthreads();
    }
    if (tid < nb) bsum[tid] = s[tid];
}

__global__ void scan_finish_kernel(int* __restrict__ outp, const int* __restrict__ bsum, int n) {
    int i = blockIdx.x * 256 + threadIdx.x;
    if (i < n) {
        if (blockIdx.x > 0) outp[i + 1] += bsum[blockIdx.x - 1];
    }
    if (i == 0) outp[0] = 0;
}

// scatter edges into packed class buckets (LDS cursors only, 4B payload)
__global__ __launch_bounds__(256) void scatter_bin_kernel(const int* __restrict__ ei,
                                                          const int* __restrict__ blkoff,
                                                          unsigned int* __restrict__ ebin) {
    __shared__ int cur[NCLS];
    for (int c = threadIdx.x; c < NCLS; c += 256) cur[c] = blkoff[c * NBLKH + blockIdx.x];
    __syncthreads();
    int base = blockIdx.x * EPB;
#pragma unroll
    for (int i = 0; i < 16; ++i) {
        int idx = base + i * 256 + threadIdx.x;
        if (idx < EE) {
            int s = __builtin_nontemporal_load(ei + idx);
            int d = __builtin_nontemporal_load(ei + EE + idx);
            int c = (unsigned)d / CLSW;
            int pos = atomicAdd(&cur[c], 1);
            ebin[pos] = ((unsigned)(d - c * CLSW) << 17) | (unsigned)s;
        }
    }
}

// one block per class: LDS degree count -> row_ptr (class-local prefix scan) + dinv.
__global__ __launch_bounds__(256) void count_dinv_kernel(const unsigned int* __restrict__ ebin,
                                                         const int* __restrict__ blkoff,
                                                         int* __restrict__ row_ptr,
                                                         float* __restrict__ dinv) {
    __shared__ int cnt[CLSW];
    __shared__ int part[256];
    int c = blockIdx.x;
    for (int i = threadIdx.x; i < CLSW; i += 256) cnt[i] = 0;
    __syncthreads();
    int beg = blkoff[c * NBLKH];
    int end = blkoff[(c + 1) * NBLKH];   // blkoff[SCAN_N] == EE
    int n0 = c * CLSW;
    for (int k = beg + threadIdx.x; k < end; k += 256) {
        unsigned int e = __builtin_nontemporal_load(ebin + k);
        atomicAdd(&cnt[e >> 17], 1);
    }
    __syncthreads();
    int nn = min(n0 + CLSW, NN) - n0;
    int t = threadIdx.x;
    int base = t * 4;
    int lpre[4];
    int lsum = 0;
#pragma unroll
    for (int i = 0; i < 4; ++i) {
        int idx = base + i;
        int v = (idx < nn) ? cnt[idx] : 0;
        lpre[i] = lsum;
        lsum += v;
    }
    part[t] = lsum;
    __syncthreads();
    for (int off = 1; off < 256; off <<= 1) {
        int y = (t >= off) ? part[t - off] : 0;
        __syncthreads();
        part[t] += y;
        __syncthreads();
    }
    int add = beg + ((t > 0) ? part[t - 1] : 0);
#pragma unroll
    for (int i = 0; i < 4; ++i) {
        int idx = base + i;
        if (idx < nn) {
            row_ptr[n0 + idx] = add + lpre[i];
            dinv[n0 + idx] = 1.0f / sqrtf((float)(cnt[idx] + 1));  // +1 self loop
        }
    }
    if (t == 0) row_ptr[n0 + nn] = end;   // class boundary (last class writes row_ptr[NN]=EE)
}

// one block per class: LDS cursors from row_ptr, fill col (class-owned col range).
__global__ __launch_bounds__(256) void fill_class_kernel(const unsigned int* __restrict__ ebin,
                                                         const int* __restrict__ blkoff,
                                                         const int* __restrict__ row_ptr,
                                                         int* __restrict__ col) {
    __shared__ int cur[CLSW];
    int c = blockIdx.x;
    int n0 = c * CLSW;
    int nn = min(n0 + CLSW, NN) - n0;
    for (int i = threadIdx.x; i < nn; i += 256) cur[i] = row_ptr[n0 + i];
    __syncthreads();
    int beg = blkoff[c * NBLKH];
    int end = blkoff[(c + 1) * NBLKH];
    for (int k = beg + threadIdx.x; k < end; k += 256) {
        unsigned int e = __builtin_nontemporal_load(ebin + k);
        int o = atomicAdd(&cur[e >> 17], 1);
        col[o] = (int)(e & 0x1FFFFu);
    }
}

// ---------------- W transpose precompute: Wt[c][k] = (fp16) W[k][c], 3 matrices -------------

__global__ __launch_bounds__(256) void wt_kernel(const float* __restrict__ W1,
                                                 const float* __restrict__ W2,
                                                 const float* __restrict__ W3,
                                                 _Float16* __restrict__ wt) {
    int m = blockIdx.y;
    const float* W = (m == 0) ? W1 : ((m == 1) ? W2 : W3);
    _Float16* o = wt + (size_t)m * 16384;
    int f = blockIdx.x * 256 + threadIdx.x;   // float4 id in [0,4096)
    float4 v = ((const float4*)W)[f];
    int k = f >> 5;
    int c = (f & 31) << 2;
    o[(c + 0) * 128 + k] = (_Float16)v.x;
    o[(c + 1) * 128 + k] = (_Float16)v.y;
    o[(c + 2) * 128 + k] = (_Float16)v.z;
    o[(c + 3) * 128 + k] = (_Float16)v.w;
}

// ---------------- MFMA GEMM: Y[n][128](fp16, x dinv[row]) = X[n][128] @ W ----------
// B-fragments read directly from precomputed global Wt (32KB, L2-resident) — no W LDS
// staging, LDS = output buffer only (34.8KB) -> 4 blocks/CU.

#define WTP 136

template <bool IN32>
__global__ __launch_bounds__(256) void gemm_mfma_kernel(const void* __restrict__ Xv,
                                                        const _Float16* __restrict__ Wt,
                                                        const float* __restrict__ dinv,
                                                        _Float16* __restrict__ Y, int nrows) {
    __shared__ _Float16 Ob[128][WTP];   // 34.8 KB
    int tid = threadIdx.x;
    int row0 = blockIdx.x * 128;

    int wave = tid >> 6;
    int l = tid & 63;
    int arow = l & 15;
    int kg = l >> 4;                 // k-group 0..3
    int baseRow = row0 + wave * 32;

    // A fragments: lane holds X[row][ks*32 + kg*8 .. +8]
    f16x8 afrag[2][4];
#pragma unroll
    for (int rt = 0; rt < 2; ++rt) {
        int r = baseRow + rt * 16 + arow;
        r = min(r, nrows - 1);
        if (IN32) {
            const float* xr = ((const float*)Xv) + (size_t)r * 128;
#pragma unroll
            for (int ks = 0; ks < 4; ++ks) {
                int k0 = ks * 32 + kg * 8;
                float4 a = ((const float4*)xr)[k0 >> 2];
                float4 b = ((const float4*)xr)[(k0 >> 2) + 1];
                f16x8 v;
                v[0] = (_Float16)a.x; v[1] = (_Float16)a.y;
                v[2] = (_Float16)a.z; v[3] = (_Float16)a.w;
                v[4] = (_Float16)b.x; v[5] = (_Float16)b.y;
                v[6] = (_Float16)b.z; v[7] = (_Float16)b.w;
                afrag[rt][ks] = v;
            }
        } else {
            const f16x8* xr = (const f16x8*)(((const _Float16*)Xv) + (size_t)r * 128);
#pragma unroll
            for (int ks = 0; ks < 4; ++ks) afrag[rt][ks] = xr[ks * 4 + kg];
        }
    }

    f32x4 acc[2][8];
#pragma unroll
    for (int rt = 0; rt < 2; ++rt)
#pragma unroll
        for (int ct = 0; ct < 8; ++ct) acc[rt][ct] = (f32x4){0.f, 0.f, 0.f, 0.f};

#pragma unroll
    for (int ct = 0; ct < 8; ++ct) {
#pragma unroll
        for (int ks = 0; ks < 4; ++ks) {
            f16x8 b = *(const f16x8*)(Wt + (size_t)(ct * 16 + arow) * 128 + ks * 32 + kg * 8);
            acc[0][ct] = __builtin_amdgcn_mfma_f32_16x16x32_f16(afrag[0][ks], b, acc[0][ct], 0, 0, 0);
            acc[1][ct] = __builtin_amdgcn_mfma_f32_16x16x32_f16(afrag[1][ks], b, acc[1][ct], 0, 0, 0);
        }
    }

    // dinv for the 8 rows this lane owns (D: row = rt*16 + 4*kg + j, col = arow)
    float dv[2][4];
#pragma unroll
    for (int rt = 0; rt < 2; ++rt)
#pragma unroll
        for (int j = 0; j < 4; ++j) {
            int r = baseRow + rt * 16 + 4 * kg + j;
            dv[rt][j] = dinv[min(r, nrows - 1)];
        }

    // stage to LDS (own wave's 32 rows only — no block sync needed)
#pragma unroll
    for (int rt = 0; rt < 2; ++rt)
#pragma unroll
        for (int ct = 0; ct < 8; ++ct)
#pragma unroll
            for (int j = 0; j < 4; ++j)
                Ob[wave * 32 + rt * 16 + 4 * kg + j][ct * 16 + arow] =
                    (_Float16)(acc[rt][ct][j] * dv[rt][j]);

    // coalesced write-back: 8 x 16B per lane
#pragma unroll
    for (int i = 0; i < 8; ++i) {
        int q = i * 64 + l;          // [0,512): 32 rows x 16 chunks
        int lrow = q >> 4;
        int c = q & 15;
        int r = baseRow + lrow;
        if (r < nrows) {
            f16x8 v = *(const f16x8*)&Ob[wave * 32 + lrow][c * 8];
            *(f16x8*)(Y + (size_t)r * 128 + c * 8) = v;
        }
    }
}

// ---------------- GCN aggregation (R12 proven version: 8-deep, VGPR 24) ----------------
// one wave per node, lane = half2 feature slot; edge loop unrolled x8 with 4
// independent accumulators. out = relu(dinv[i]*(sum hw'[col] + hw'[i]) + b), fp16 out.

__global__ __launch_bounds__(256) void aggregate_kernel(const __half* __restrict__ hw,
                                                        const int* __restrict__ rp,
                                                        const int* __restrict__ col,
                                                        const float* __restrict__ dinv,
                                                        const float* __restrict__ bias,
                                                        __half* __restrict__ outp, int n) {
    int wid = threadIdx.x >> 6;
    int lane = threadIdx.x & 63;
    int i = blockIdx.x * 4 + wid;
    if (i >= n) return;
    const __half2* hw2 = (const __half2*)hw;  // row = 64 half2 (256B)
    float2 a0, a1, a2, a3;
    {
        float2 self = __half22float2(hw2[(size_t)i * 64 + lane]);
        a0.x = self.x; a0.y = self.y;
    }
    a1 = make_float2(0.f, 0.f);
    a2 = make_float2(0.f, 0.f);
    a3 = make_float2(0.f, 0.f);
    int j0 = rp[i], j1 = rp[i + 1];
    int j = j0;
    for (; j + 8 <= j1; j += 8) {
        int s0 = col[j + 0];
        int s1 = col[j + 1];
        int s2 = col[j + 2];
        int s3 = col[j + 3];
        int s4 = col[j + 4];
        int s5 = col[j + 5];
        int s6 = col[j + 6];
        int s7 = col[j + 7];
        __half2 v0 = hw2[(size_t)s0 * 64 + lane];
        __half2 v1 = hw2[(size_t)s1 * 64 + lane];
        __half2 v2 = hw2[(size_t)s2 * 64 + lane];
        __half2 v3 = hw2[(size_t)s3 * 64 + lane];
        __half2 v4 = hw2[(size_t)s4 * 64 + lane];
        __half2 v5 = hw2[(size_t)s5 * 64 + lane];
        __half2 v6 = hw2[(size_t)s6 * 64 + lane];
        __half2 v7 = hw2[(size_t)s7 * 64 + lane];
        float2 f;
        f = __half22float2(v0); a0.x += f.x; a0.y += f.y;
        f = __half22float2(v1); a1.x += f.x; a1.y += f.y;
        f = __half22float2(v2); a2.x += f.x; a2.y += f.y;
        f = __half22float2(v3); a3.x += f.x; a3.y += f.y;
        f = __half22float2(v4); a0.x += f.x; a0.y += f.y;
        f = __half22float2(v5); a1.x += f.x; a1.y += f.y;
        f = __half22float2(v6); a2.x += f.x; a2.y += f.y;
        f = __half22float2(v7); a3.x += f.x; a3.y += f.y;
    }
    for (; j + 4 <= j1; j += 4) {
        int s0 = col[j + 0];
        int s1 = col[j + 1];
        int s2 = col[j + 2];
        int s3 = col[j + 3];
        __half2 v0 = hw2[(size_t)s0 * 64 + lane];
        __half2 v1 = hw2[(size_t)s1 * 64 + lane];
        __half2 v2 = hw2[(size_t)s2 * 64 + lane];
        __half2 v3 = hw2[(size_t)s3 * 64 + lane];
        float2 f;
        f = __half22float2(v0); a0.x += f.x; a0.y += f.y;
        f = __half22float2(v1); a1.x += f.x; a1.y += f.y;
        f = __half22float2(v2); a2.x += f.x; a2.y += f.y;
        f = __half22float2(v3); a3.x += f.x; a3.y += f.y;
    }
    for (; j < j1; ++j) {
        int s = col[j];
        float2 f = __half22float2(hw2[(size_t)s * 64 + lane]);
        a0.x += f.x; a0.y += f.y;
    }
    float di = dinv[i];
    float2 acc;
    acc.x = ((a0.x + a1.x) + (a2.x + a3.x)) * di;
    acc.y = ((a0.y + a1.y) + (a2.y + a3.y)) * di;
    float2 bv = ((const float2*)bias)[lane];
    float rx = fmaxf(acc.x + bv.x, 0.f);
    float ry = fmaxf(acc.y + bv.y, 0.f);
    ((__half2*)outp)[(size_t)i * 64 + lane] = __floats2half2_rn(rx, ry);
}

// ---------------- fused mean-pool + DeepSets psi (one block per graph) ----------------

__global__ __launch_bounds__(256) void poolpsi_kernel(const __half* __restrict__ h,
                                                      const float* __restrict__ W1,
                                                      const float* __restrict__ b1,
                                                      const float* __restrict__ W2,
                                                      const float* __restrict__ b2,
                                                      float* __restrict__ pbuf) {
    __shared__ float2 part[4][64];
    __shared__ float e[128];
    __shared__ float t[128];
    int g = blockIdx.x;
    int q = threadIdx.x & 63;
    int rg = threadIdx.x >> 6;
    const __half2* h2 = (const __half2*)h;
    size_t base = (size_t)g * NPG * 64;
    float2 acc = {0.f, 0.f};
    for (int r = rg; r < NPG; r += 4) {
        float2 v = __half22float2(h2[base + (size_t)r * 64 + q]);
        acc.x += v.x;
        acc.y += v.y;
    }
    part[rg][q] = acc;
    __syncthreads();
    if (threadIdx.x < 64) {
        float2 s0 = part[0][threadIdx.x];
        float2 s1 = part[1][threadIdx.x];
        float2 s2 = part[2][threadIdx.x];
        float2 s3 = part[3][threadIdx.x];
        e[2 * threadIdx.x]     = ((s0.x + s1.x) + (s2.x + s3.x)) * (1.0f / NPG);
        e[2 * threadIdx.x + 1] = ((s0.y + s1.y) + (s2.y + s3.y)) * (1.0f / NPG);
    }
    __syncthreads();
    int c = threadIdx.x;
    if (c < 128) {
        float acc1 = b1[c];
#pragma unroll 8
        for (int k = 0; k < 128; ++k) acc1 += e[k] * W1[k * 128 + c];
        t[c] = fmaxf(acc1, 0.f);
    }
    __syncthreads();
    if (c < 128) {
        float acc2 = b2[c];
#pragma unroll 8
        for (int k = 0; k < 128; ++k) acc2 += t[k] * W2[k * 128 + c];
        pbuf[(size_t)g * 128 + c] = tanhf(acc2);
    }
}

// ---------------- set-sum + phi head ----------------

__global__ __launch_bounds__(128) void phi_kernel(const float* __restrict__ pbuf,
                                                  const float* __restrict__ W1,
                                                  const float* __restrict__ b1,
                                                  const float* __restrict__ W2,
                                                  const float* __restrict__ b2,
                                                  float* __restrict__ out) {
    __shared__ float a[128];
    __shared__ float u[128];
    int s = blockIdx.x;
    int c = threadIdx.x;
    float acc = 0.f;
#pragma unroll
    for (int p = 0; p < PGS; ++p) acc += pbuf[(size_t)(s + p * SS) * 128 + c];
    a[c] = acc;
    __syncthreads();
    float acc1 = b1[c];
#pragma unroll 8
    for (int k = 0; k < 128; ++k) acc1 += a[k] * W1[k * 128 + c];
    u[c] = fmaxf(acc1, 0.f);
    __syncthreads();
    if (c < CC) {
        float acc2 = b2[c];
#pragma unroll 8
        for (int k = 0; k < 128; ++k) acc2 += u[k] * W2[k * CC + c];
        out[(size_t)s * CC + c] = acc2;
    }
}

// ---------------- launch ----------------

extern "C" void kernel_launch(void* const* d_in, const int* in_sizes, int n_in,
                              void* d_out, int out_size, void* d_ws, size_t ws_size,
                              hipStream_t stream) {
    const float* x   = (const float*)d_in[0];
    const int* ei    = (const int*)d_in[1];
    const float* W1  = (const float*)d_in[4];
    const float* b1  = (const float*)d_in[5];
    const float* W2  = (const float*)d_in[6];
    const float* b2  = (const float*)d_in[7];
    const float* W3  = (const float*)d_in[8];
    const float* b3  = (const float*)d_in[9];
    const float* pW1 = (const float*)d_in[10];
    const float* pb1 = (const float*)d_in[11];
    const float* pW2 = (const float*)d_in[12];
    const float* pb2 = (const float*)d_in[13];
    const float* fW1 = (const float*)d_in[14];
    const float* fb1 = (const float*)d_in[15];
    const float* fW2 = (const float*)d_in[16];
    const float* fb2 = (const float*)d_in[17];
    float* out = (float*)d_out;

    // workspace carve-up (256B aligned)
    char* p = (char*)d_ws;
    auto alloc = [&](size_t bytes) {
        char* r = p;
        p += (bytes + 255) & ~(size_t)255;
        return r;
    };
    float*        dinv    = (float*)alloc((size_t)NN * 4);
    int*          row_ptr = (int*)alloc((size_t)(NN + 1) * 4);
    int*          bsum2   = (int*)alloc(512 * 4);
    int*          blkcnt  = (int*)alloc((size_t)SCAN_N * 4);
    int*          blkoff  = (int*)alloc((size_t)(SCAN_N + 1) * 4);
    int*          col     = (int*)alloc((size_t)EE * 4);
    unsigned int* ebin    = (unsigned int*)alloc((size_t)EE * 4);   // 6.4 MB packed buckets
    _Float16*     wtbuf   = (_Float16*)alloc((size_t)3 * 16384 * 2); // 3 transposed fp16 weights
    _Float16*     bufA    = (_Float16*)alloc((size_t)NN * HH * 2);  // dinv-scaled XW (gather operand)
    __half*       bufB    = (__half*)alloc((size_t)NN * HH * 2);    // relu'd layer output
    float*        pbuf    = (float*)alloc((size_t)GG * HH * 4);

    const int nblkS = (SCAN_N + 255) / 256;    // 196

    // weight transposes (independent of CSR chain)
    wt_kernel<<<dim3(16, 3), 256, 0, stream>>>(W1, W2, W3, wtbuf);

    // CSR build (deterministic binned, class-owned)
    histo_kernel<<<NBLKH, 256, 0, stream>>>(ei + EE, blkcnt);
    scan_chunk_kernel<<<nblkS, 256, 0, stream>>>(blkcnt, blkoff, bsum2, SCAN_N);
    scan_bsums_kernel<<<1, 512, 0, stream>>>(bsum2, nblkS);
    scan_finish_kernel<<<nblkS, 256, 0, stream>>>(blkoff, bsum2, SCAN_N);
    scatter_bin_kernel<<<NBLKH, 256, 0, stream>>>(ei, blkoff, ebin);
    count_dinv_kernel<<<NCLS, 256, 0, stream>>>(ebin, blkoff, row_ptr, dinv);
    fill_class_kernel<<<NCLS, 256, 0, stream>>>(ebin, blkoff, row_ptr, col);

    const int gemmBlocks = (NN + 127) / 128;   // 782
    const int aggBlocks  = (NN + 3) / 4;       // 25000

    // layer 1
    gemm_mfma_kernel<true><<<gemmBlocks, 256, 0, stream>>>(x, wtbuf, dinv, bufA, NN);
    aggregate_kernel<<<aggBlocks, 256, 0, stream>>>((const __half*)bufA, row_ptr, col, dinv, b1, bufB, NN);
    // layer 2
    gemm_mfma_kernel<false><<<gemmBlocks, 256, 0, stream>>>(bufB, wtbuf + 16384, dinv, bufA, NN);
    aggregate_kernel<<<aggBlocks, 256, 0, stream>>>((const __half*)bufA, row_ptr, col, dinv, b2, bufB, NN);
    // layer 3
    gemm_mfma_kernel<false><<<gemmBlocks, 256, 0, stream>>>(bufB, wtbuf + 32768, dinv, bufA, NN);
    aggregate_kernel<<<aggBlocks, 256, 0, stream>>>((const __half*)bufA, row_ptr, col, dinv, b3, bufB, NN);

    // fused pool+psi -> pbuf
    poolpsi_kernel<<<GG, 256, 0, stream>>>(bufB, pW1, pb1, pW2, pb2, pbuf);
    // phi head
    phi_kernel<<<SS, 128, 0, stream>>>(pbuf, fW1, fb1, fW2, fb2, out);
}